// Round 1
// baseline (468.429 us; speedup 1.0000x reference)
//
#include <hip/hip_runtime.h>

// Problem constants (from reference): B=32 graphs, N=1024 nodes/graph, F=64, D=128, DEG=8
#define E_TOTAL 262144     // B*N*DEG
#define NGRAPH  32
#define EPG     8192       // edges per graph
#define EPS_BN  1e-5f

__device__ __forceinline__ float lrelu(float x){ return x > 0.f ? x : 0.2f * x; }

// ---------------- mask init: remove original self loops ----------------
__global__ void init_mask_kernel(const int* __restrict__ src, const int* __restrict__ dst,
                                 unsigned char* __restrict__ mask){
  int e = blockIdx.x * blockDim.x + threadIdx.x;
  if (e < E_TOTAL) mask[e] = (src[e] != dst[e]) ? 1 : 0;
}

// ---------------- GEMM: C[M,128] = A[M,K] @ W[K,128], f32 vector ALU ----------------
// block = 256 threads, 16 rows per block; W staged in 64-row LDS chunks, A tile in LDS.
template<int K>
__global__ void gemm_xw(const float* __restrict__ A, const float* __restrict__ W,
                        float* __restrict__ C, int M){
  __shared__ float Ws[64 * 128];   // 32 KB
  __shared__ float As[16 * K];     // 4 or 8 KB
  int row0blk = blockIdx.x * 16;
  for (int i = threadIdx.x; i < 16 * K; i += 256)
    As[i] = A[(size_t)row0blk * K + i];
  int c  = threadIdx.x & 127;
  int yg = threadIdx.x >> 7;       // 0..1
  float acc[8] = {0.f,0.f,0.f,0.f,0.f,0.f,0.f,0.f};
  for (int k0 = 0; k0 < K; k0 += 64){
    __syncthreads();
    for (int i = threadIdx.x; i < 64 * 128; i += 256)
      Ws[i] = W[(size_t)k0 * 128 + i];
    __syncthreads();
    for (int kk = 0; kk < 64; ++kk){
      float w = Ws[kk * 128 + c];
      #pragma unroll
      for (int i = 0; i < 8; ++i)
        acc[i] = fmaf(As[(yg * 8 + i) * K + k0 + kk], w, acc[i]);
    }
  }
  #pragma unroll
  for (int i = 0; i < 8; ++i)
    C[(size_t)(row0blk + yg * 8 + i) * 128 + c] = acc[i];
}

// ---------------- per-node attention terms: es = h.a_s, ed = h.a_d ----------------
// one wave per node; lane handles channels (2*lane, 2*lane+1)
__global__ void attn_terms(const float* __restrict__ h, const float* __restrict__ a_s,
                           const float* __restrict__ a_d, float* __restrict__ es,
                           float* __restrict__ ed, int M){
  int lane = threadIdx.x & 63;
  int n = blockIdx.x * 4 + (threadIdx.x >> 6);
  if (n >= M) return;
  float2 hv  = ((const float2*)h)[(size_t)n * 64 + lane];
  float2 as2 = ((const float2*)a_s)[lane];
  float2 ad2 = ((const float2*)a_d)[lane];
  float e1 = hv.x * as2.x + hv.y * as2.y;
  float e2 = hv.x * ad2.x + hv.y * ad2.y;
  #pragma unroll
  for (int o = 32; o; o >>= 1){ e1 += __shfl_xor(e1, o); e2 += __shfl_xor(e2, o); }
  if (lane == 0){ es[n] = e1; ed[n] = e2; }
}

// ---------------- per-graph counting sort of masked edges by dst ----------------
// one block per graph; Npg <= 1024 (power of two)
__global__ void build_csr(const int* __restrict__ dst0, const unsigned char* __restrict__ mask,
                          int* __restrict__ csr_eid, int* __restrict__ row_start,
                          int* __restrict__ row_cnt, int shift, int Npg){
  __shared__ int cnt[1024];
  __shared__ int pos[1024];
  int g = blockIdx.x;
  int ebase = g * EPG;
  for (int i = threadIdx.x; i < Npg; i += 256) cnt[i] = 0;
  __syncthreads();
  for (int j = threadIdx.x; j < EPG; j += 256){
    int e = ebase + j;
    if (mask[e]){
      int d = (dst0[e] >> shift) & (Npg - 1);
      atomicAdd(&cnt[d], 1);
    }
  }
  __syncthreads();
  if (threadIdx.x == 0){
    int run = 0;
    for (int i = 0; i < Npg; ++i){ pos[i] = run; run += cnt[i]; }
  }
  __syncthreads();
  int nodebase = g * Npg;
  for (int i = threadIdx.x; i < Npg; i += 256){
    row_start[nodebase + i] = ebase + pos[i];
    row_cnt[nodebase + i]   = cnt[i];
  }
  __syncthreads();
  for (int j = threadIdx.x; j < EPG; j += 256){
    int e = ebase + j;
    if (mask[e]){
      int d = (dst0[e] >> shift) & (Npg - 1);
      int p = atomicAdd(&pos[d], 1);
      csr_eid[ebase + p] = e;
    }
  }
}

// ---------------- GAT softmax-aggregate, one wave per destination node ----------------
// includes the implicit self loop; applies bias + ReLU
__global__ void gat_agg(const float* __restrict__ h, const float* __restrict__ es,
                        const float* __restrict__ ed, const int* __restrict__ src0,
                        const int* __restrict__ csr_eid, const int* __restrict__ row_start,
                        const int* __restrict__ row_cnt, const float* __restrict__ bias,
                        float* __restrict__ out, int M, int shift){
  int lane = threadIdx.x & 63;
  int n = blockIdx.x * 4 + (threadIdx.x >> 6);
  if (n >= M) return;
  int start = row_start[n];
  int cnt   = row_cnt[n];
  float edn = ed[n];
  float selfl = lrelu(es[n] + edn);
  // pass 1: max logit (lane-parallel over edges)
  float m = selfl;
  for (int j = lane; j < cnt; j += 64){
    int s = src0[csr_eid[start + j]] >> shift;
    m = fmaxf(m, lrelu(es[s] + edn));
  }
  #pragma unroll
  for (int o = 32; o; o >>= 1) m = fmaxf(m, __shfl_xor(m, o));
  // pass 2: denominator
  float den = 0.f;
  for (int j = lane; j < cnt; j += 64){
    int s = src0[csr_eid[start + j]] >> shift;
    den += expf(lrelu(es[s] + edn) - m);
  }
  #pragma unroll
  for (int o = 32; o; o >>= 1) den += __shfl_xor(den, o);
  float selfw = expf(selfl - m);
  den += selfw;
  // pass 3: weighted vector accumulation; lane holds channels (2*lane, 2*lane+1)
  const float2* h2 = (const float2*)h;
  float2 hv = h2[(size_t)n * 64 + lane];
  float2 acc; acc.x = selfw * hv.x; acc.y = selfw * hv.y;
  for (int j = 0; j < cnt; ++j){
    int s = src0[csr_eid[start + j]] >> shift;
    float w = expf(lrelu(es[s] + edn) - m);
    float2 hs = h2[(size_t)s * 64 + lane];
    acc.x = fmaf(w, hs.x, acc.x);
    acc.y = fmaf(w, hs.y, acc.y);
  }
  float inv = 1.f / den;
  float2 bv = ((const float2*)bias)[lane];
  float2 o2;
  o2.x = fmaxf(acc.x * inv + bv.x, 0.f);
  o2.y = fmaxf(acc.y * inv + bv.y, 0.f);
  ((float2*)out)[(size_t)n * 64 + lane] = o2;
}

// ---------------- pairwise max-pool over nodes (cluster map = node>>1) ----------------
__global__ void pool_max(const float* __restrict__ in, float* __restrict__ out, int Mout){
  int idx = blockIdx.x * blockDim.x + threadIdx.x;   // Mout*32 float4 slots
  if (idx >= Mout * 32) return;
  int n = idx >> 5, c = idx & 31;
  float4 a = ((const float4*)in)[(size_t)(2 * n) * 32 + c];
  float4 b = ((const float4*)in)[(size_t)(2 * n + 1) * 32 + c];
  float4 r;
  r.x = fmaxf(a.x, b.x); r.y = fmaxf(a.y, b.y);
  r.z = fmaxf(a.z, b.z); r.w = fmaxf(a.w, b.w);
  ((float4*)out)[idx] = r;
}

// ---------------- dedupe after pooling: keep one representative per (src,dst) ----------------
__global__ void dedupe_kernel(const int* __restrict__ src0, const int* __restrict__ dst0,
                              unsigned char* __restrict__ mask, unsigned int* __restrict__ bitmap,
                              int shift, int log2Npg){
  int e = blockIdx.x * blockDim.x + threadIdx.x;
  if (e >= E_TOTAL) return;
  if (!mask[e]) return;
  int s = src0[e] >> shift, d = dst0[e] >> shift;
  if (s == d){ mask[e] = 0; return; }
  int Npg = 1 << log2Npg;
  unsigned int g = (unsigned int)(s >> log2Npg);
  unsigned int key = (g << (2 * log2Npg)) | ((unsigned int)(s & (Npg - 1)) << log2Npg)
                   | (unsigned int)(d & (Npg - 1));
  unsigned int bit = 1u << (key & 31u);
  unsigned int old = atomicOr(&bitmap[key >> 5], bit);
  if (old & bit) mask[e] = 0;
}

// ---------------- BatchNorm (training stats, no affine) ----------------
__global__ void bn_stats(const float* __restrict__ x, float* __restrict__ sums, int M){
  __shared__ float s1[256], s2[256];
  int c = threadIdx.x & 127, half = threadIdx.x >> 7;
  float a = 0.f, b = 0.f;
  for (int r = blockIdx.x * 2 + half; r < M; r += gridDim.x * 2){
    float v = x[(size_t)r * 128 + c];
    a += v; b += v * v;
  }
  s1[threadIdx.x] = a; s2[threadIdx.x] = b;
  __syncthreads();
  if (threadIdx.x < 128){
    a = s1[threadIdx.x] + s1[threadIdx.x + 128];
    b = s2[threadIdx.x] + s2[threadIdx.x + 128];
    atomicAdd(&sums[c], a);
    atomicAdd(&sums[128 + c], b);
  }
}

__global__ void bn_norm(const float* __restrict__ in, const float* __restrict__ sums,
                        float* __restrict__ out, int M){
  int idx = blockIdx.x * blockDim.x + threadIdx.x;
  if (idx >= M * 128) return;
  int c = idx & 127;
  float mu  = sums[c] / (float)M;
  float var = sums[128 + c] / (float)M - mu * mu;
  out[idx] = (in[idx] - mu) * rsqrtf(var + EPS_BN);
}

extern "C" void kernel_launch(void* const* d_in, const int* in_sizes, int n_in,
                              void* d_out, int out_size, void* d_ws, size_t ws_size,
                              hipStream_t stream){
  const float* x0   = (const float*)d_in[0];   // (32768, 64)
  const float* W0   = (const float*)d_in[1];   // (64, 128)
  const float* W1   = (const float*)d_in[2];   // (128, 128)
  const float* W2   = (const float*)d_in[3];   // (128, 128)
  const float* attS = (const float*)d_in[4];   // (3, 128)
  const float* attD = (const float*)d_in[5];   // (3, 128)
  const float* bias = (const float*)d_in[6];   // (3, 128) zeros
  const int*   src0 = (const int*)d_in[7];     // edge_index row 0
  const int*   dst0 = src0 + E_TOTAL;          // edge_index row 1
  float* out = (float*)d_out;                  // (32, 16384) f32

  char* ws = (char*)d_ws;
  float*         Hbuf    = (float*)(ws);                                   // 16 MB: h = x@W
  float*         Gbuf    = (float*)(ws + (16u << 20));                     // 16 MB: gat output
  float*         Xbuf    = (float*)(ws + (32u << 20));                     //  8 MB: pooled/normed x
  float*         es      = (float*)(ws + (40u << 20));                     // 128 KB
  float*         ed      = (float*)(ws + (40u << 20) + 131072);            // 128 KB
  int*           csr_eid = (int*)  (ws + (41u << 20));                     //  1 MB
  int*           row_start = (int*)(ws + (42u << 20));                     // 128 KB
  int*           row_cnt   = (int*)(ws + (42u << 20) + 131072);            // 128 KB
  unsigned char* mask    = (unsigned char*)(ws + (43u << 20));             // 256 KB
  unsigned int*  bitmap0 = (unsigned int*)(ws + (44u << 20));              //  1 MB (32*512*512 bits)
  unsigned int*  bitmap1 = (unsigned int*)(ws + (45u << 20));              // 256 KB (32*256*256 bits)
  float*         bnsum0  = (float*)(ws + (45u << 20) + 262144);            // 256 f
  float*         bnsum1  = bnsum0 + 256;
  float*         bnsum2  = bnsum1 + 256;

  // zero the atomic scratch (bitmaps + bn sums), contiguous region
  hipMemsetAsync(ws + (44u << 20), 0, (1u << 20) + 262144 + 3 * 256 * sizeof(float), stream);

  init_mask_kernel<<<E_TOTAL / 256, 256, 0, stream>>>(src0, dst0, mask);

  // ---------------- layer 1: M=32768, K=64, shift=0 ----------------
  int M = 32768;
  gemm_xw<64><<<M / 16, 256, 0, stream>>>(x0, W0, Hbuf, M);
  attn_terms<<<M / 4, 256, 0, stream>>>(Hbuf, attS, attD, es, ed, M);
  build_csr<<<NGRAPH, 256, 0, stream>>>(dst0, mask, csr_eid, row_start, row_cnt, 0, 1024);
  gat_agg<<<M / 4, 256, 0, stream>>>(Hbuf, es, ed, src0, csr_eid, row_start, row_cnt,
                                     bias, Gbuf, M, 0);
  int Mo = M / 2;  // 16384
  pool_max<<<(Mo * 32) / 256, 256, 0, stream>>>(Gbuf, Xbuf, Mo);
  dedupe_kernel<<<E_TOTAL / 256, 256, 0, stream>>>(src0, dst0, mask, bitmap0, 1, 9);
  bn_stats<<<256, 256, 0, stream>>>(Xbuf, bnsum0, Mo);
  bn_norm<<<(Mo * 128) / 256, 256, 0, stream>>>(Xbuf, bnsum0, Xbuf, Mo);

  // ---------------- layer 2: M=16384, K=128, shift=1 ----------------
  M = 16384;
  gemm_xw<128><<<M / 16, 256, 0, stream>>>(Xbuf, W1, Hbuf, M);
  attn_terms<<<M / 4, 256, 0, stream>>>(Hbuf, attS + 128, attD + 128, es, ed, M);
  build_csr<<<NGRAPH, 256, 0, stream>>>(dst0, mask, csr_eid, row_start, row_cnt, 1, 512);
  gat_agg<<<M / 4, 256, 0, stream>>>(Hbuf, es, ed, src0, csr_eid, row_start, row_cnt,
                                     bias + 128, Gbuf, M, 1);
  Mo = 8192;
  pool_max<<<(Mo * 32) / 256, 256, 0, stream>>>(Gbuf, Xbuf, Mo);
  dedupe_kernel<<<E_TOTAL / 256, 256, 0, stream>>>(src0, dst0, mask, bitmap1, 2, 8);
  bn_stats<<<256, 256, 0, stream>>>(Xbuf, bnsum1, Mo);
  bn_norm<<<(Mo * 128) / 256, 256, 0, stream>>>(Xbuf, bnsum1, Xbuf, Mo);

  // ---------------- layer 3: M=8192, K=128, shift=2 ----------------
  M = 8192;
  gemm_xw<128><<<M / 16, 256, 0, stream>>>(Xbuf, W2, Hbuf, M);
  attn_terms<<<M / 4, 256, 0, stream>>>(Hbuf, attS + 256, attD + 256, es, ed, M);
  build_csr<<<NGRAPH, 256, 0, stream>>>(dst0, mask, csr_eid, row_start, row_cnt, 2, 256);
  gat_agg<<<M / 4, 256, 0, stream>>>(Hbuf, es, ed, src0, csr_eid, row_start, row_cnt,
                                     bias + 256, Gbuf, M, 2);
  Mo = 4096;
  pool_max<<<(Mo * 32) / 256, 256, 0, stream>>>(Gbuf, Xbuf, Mo);
  bn_stats<<<256, 256, 0, stream>>>(Xbuf, bnsum2, Mo);
  bn_norm<<<(Mo * 128) / 256, 256, 0, stream>>>(Xbuf, bnsum2, out, Mo);  // final: 4096*128 = out
}

// Round 2
// 290.364 us; speedup vs baseline: 1.6132x; 1.6132x over previous
//
#include <hip/hip_runtime.h>

// Problem constants: B=32 graphs, N=1024 nodes/graph, F=64, D=128, DEG=8
#define E_TOTAL 262144     // B*N*DEG
#define NGRAPH  32
#define EPG     8192       // edges per graph
#define EPS_BN  1e-5f

__device__ __forceinline__ float lrelu(float x){ return x > 0.f ? x : 0.2f * x; }

// ---------------- GEMM: C[M,128] = bn(A)[M,K] @ W[K,128] ----------------
// block 256 = 64 channel-pairs x 4 row-groups; 32 rows/block.
// A tile staged TRANSPOSED in LDS (stride 36 => 16B-aligned float4 reads, broadcast).
// bnsums != nullptr: normalize A columns with batch stats (sums[c], sums[128+c]).
template<int K>
__global__ __launch_bounds__(256)
void gemm_xw(const float* __restrict__ A, const float* __restrict__ W,
             const float* __restrict__ bnsums, float invM,
             float* __restrict__ C, int M){
  __shared__ float Ws[64 * 128];    // 32 KB
  __shared__ float As_t[64 * 36];   // 9 KB, [kk][row] padded
  __shared__ float bnmu[K], bnrs[K];
  int tid = threadIdx.x;
  if (tid < K){
    float mu = 0.f, rs = 1.f;
    if (bnsums){
      mu = bnsums[tid] * invM;
      float var = bnsums[K + tid] * invM - mu * mu;
      rs = rsqrtf(var + EPS_BN);
    }
    bnmu[tid] = mu; bnrs[tid] = rs;
  }
  int row0 = blockIdx.x * 32;
  int c2 = tid & 63, rg = tid >> 6;
  float2 acc[8];
  #pragma unroll
  for (int i = 0; i < 8; ++i){ acc[i].x = 0.f; acc[i].y = 0.f; }

  for (int k0 = 0; k0 < K; k0 += 64){
    __syncthreads();
    for (int i = tid; i < 64 * 128; i += 256)
      Ws[i] = W[(size_t)(k0 + (i >> 7)) * 128 + (i & 127)];
    #pragma unroll
    for (int it = 0; it < 8; ++it){
      int i = it * 256 + tid;
      int r = i >> 6, kk = i & 63;
      float v = A[(size_t)(row0 + r) * K + k0 + kk];
      v = (v - bnmu[k0 + kk]) * bnrs[k0 + kk];
      As_t[kk * 36 + r] = v;
    }
    __syncthreads();
    #pragma unroll 8
    for (int kk = 0; kk < 64; ++kk){
      float2 w = *(float2*)&Ws[kk * 128 + c2 * 2];
      float4 a0 = *(float4*)&As_t[kk * 36 + rg * 8];
      float4 a1 = *(float4*)&As_t[kk * 36 + rg * 8 + 4];
      acc[0].x = fmaf(a0.x, w.x, acc[0].x); acc[0].y = fmaf(a0.x, w.y, acc[0].y);
      acc[1].x = fmaf(a0.y, w.x, acc[1].x); acc[1].y = fmaf(a0.y, w.y, acc[1].y);
      acc[2].x = fmaf(a0.z, w.x, acc[2].x); acc[2].y = fmaf(a0.z, w.y, acc[2].y);
      acc[3].x = fmaf(a0.w, w.x, acc[3].x); acc[3].y = fmaf(a0.w, w.y, acc[3].y);
      acc[4].x = fmaf(a1.x, w.x, acc[4].x); acc[4].y = fmaf(a1.x, w.y, acc[4].y);
      acc[5].x = fmaf(a1.y, w.x, acc[5].x); acc[5].y = fmaf(a1.y, w.y, acc[5].y);
      acc[6].x = fmaf(a1.z, w.x, acc[6].x); acc[6].y = fmaf(a1.z, w.y, acc[6].y);
      acc[7].x = fmaf(a1.w, w.x, acc[7].x); acc[7].y = fmaf(a1.w, w.y, acc[7].y);
    }
  }
  float2* C2 = (float2*)C;
  #pragma unroll
  for (int i = 0; i < 8; ++i)
    C2[(size_t)(row0 + rg * 8 + i) * 64 + c2] = acc[i];
}

// ---------------- per-node attention terms: es = h.a_s, ed = h.a_d ----------------
__global__ void attn_terms(const float* __restrict__ h, const float* __restrict__ a_s,
                           const float* __restrict__ a_d, float* __restrict__ es,
                           float* __restrict__ ed, int M){
  int lane = threadIdx.x & 63;
  int n = blockIdx.x * 4 + (threadIdx.x >> 6);
  if (n >= M) return;
  float2 hv  = ((const float2*)h)[(size_t)n * 64 + lane];
  float2 as2 = ((const float2*)a_s)[lane];
  float2 ad2 = ((const float2*)a_d)[lane];
  float e1 = hv.x * as2.x + hv.y * as2.y;
  float e2 = hv.x * ad2.x + hv.y * ad2.y;
  #pragma unroll
  for (int o = 32; o; o >>= 1){ e1 += __shfl_xor(e1, o); e2 += __shfl_xor(e2, o); }
  if (lane == 0){ es[n] = e1; ed[n] = e2; }
}

// ---------------- per-graph counting sort by dst; emits shifted src directly ----------------
__global__ __launch_bounds__(1024)
void build_csr(const int* __restrict__ src0, const int* __restrict__ dst0,
               const unsigned char* __restrict__ mask,
               int* __restrict__ csr_src, int* __restrict__ row_start,
               int* __restrict__ row_cnt, int shift, int Npg, int useMask){
  __shared__ int cnt[1024];
  __shared__ int pos[1024];
  __shared__ int wsum[16];
  int g = blockIdx.x, t = threadIdx.x;
  int ebase = g * EPG;
  if (t < Npg) cnt[t] = 0;
  __syncthreads();
  for (int j = t; j < EPG; j += 1024){
    int e = ebase + j;
    bool act = useMask ? (mask[e] != 0) : (src0[e] != dst0[e]);
    if (act){
      int d = (dst0[e] >> shift) & (Npg - 1);
      atomicAdd(&cnt[d], 1);
    }
  }
  __syncthreads();
  int c = (t < Npg) ? cnt[t] : 0;
  int lane = t & 63, w = t >> 6;
  int v = c;
  #pragma unroll
  for (int o = 1; o < 64; o <<= 1){
    int u = __shfl_up(v, o);
    if (lane >= o) v += u;
  }
  if (lane == 63) wsum[w] = v;
  __syncthreads();
  if (t == 0){
    int run = 0;
    #pragma unroll
    for (int i = 0; i < 16; ++i){ int x = wsum[i]; wsum[i] = run; run += x; }
  }
  __syncthreads();
  int excl = v - c + wsum[w];
  if (t < Npg){
    pos[t] = excl;
    row_start[g * Npg + t] = ebase + excl;
    row_cnt[g * Npg + t]   = c;
  }
  __syncthreads();
  for (int j = t; j < EPG; j += 1024){
    int e = ebase + j;
    bool act = useMask ? (mask[e] != 0) : (src0[e] != dst0[e]);
    if (act){
      int d = (dst0[e] >> shift) & (Npg - 1);
      int p = atomicAdd(&pos[d], 1);
      csr_src[ebase + p] = src0[e] >> shift;
    }
  }
}

// ---------------- GAT softmax-aggregate: one wave per destination node ----------------
// Single lane-parallel logit pass + online-softmax merge; accumulation gathers
// 8 h-rows in flight via shfl-broadcast indices.
__global__ void gat_agg(const float* __restrict__ h, const float* __restrict__ es,
                        const float* __restrict__ ed, const int* __restrict__ csr_src,
                        const int* __restrict__ row_start, const int* __restrict__ row_cnt,
                        const float* __restrict__ bias, float* __restrict__ out, int M){
  int lane = threadIdx.x & 63;
  int n = blockIdx.x * 4 + (threadIdx.x >> 6);
  if (n >= M) return;
  int start = row_start[n];
  int cnt   = row_cnt[n];
  float edn = ed[n];
  float selfl = lrelu(es[n] + edn);

  // phase A: online softmax stats, lane-parallel
  float m_l = -1e30f, d_l = 0.f;
  for (int c0 = 0; c0 < cnt; c0 += 64){
    int j = c0 + lane;
    if (j < cnt){
      int s = csr_src[start + j];
      float l = lrelu(es[s] + edn);
      float mn = fmaxf(m_l, l);
      d_l = d_l * __expf(m_l - mn) + __expf(l - mn);
      m_l = mn;
    }
  }
  #pragma unroll
  for (int o = 32; o; o >>= 1){
    float m2 = __shfl_xor(m_l, o), d2 = __shfl_xor(d_l, o);
    float mn = fmaxf(m_l, m2);
    d_l = d_l * __expf(m_l - mn) + d2 * __expf(m2 - mn);
    m_l = mn;
  }
  float mf  = fmaxf(m_l, selfl);
  float den = d_l * __expf(m_l - mf) + __expf(selfl - mf);

  // phase B: weighted accumulation, 8 gathers in flight
  const float2* h2 = (const float2*)h;
  float sw = __expf(selfl - mf);
  float2 hv = h2[(size_t)n * 64 + lane];
  float2 acc; acc.x = sw * hv.x; acc.y = sw * hv.y;
  for (int c0 = 0; c0 < cnt; c0 += 64){
    int j = c0 + lane;
    int s_j = 0; float w_j = 0.f;
    if (j < cnt){
      s_j = csr_src[start + j];
      w_j = __expf(lrelu(es[s_j] + edn) - mf);
    }
    int rem = min(64, cnt - c0);
    int k = 0;
    for (; k + 8 <= rem; k += 8){
      int ss[8]; float ww[8]; float2 hh[8];
      #pragma unroll
      for (int i = 0; i < 8; ++i){ ss[i] = __shfl(s_j, k + i); ww[i] = __shfl(w_j, k + i); }
      #pragma unroll
      for (int i = 0; i < 8; ++i){ hh[i] = h2[(size_t)ss[i] * 64 + lane]; }
      #pragma unroll
      for (int i = 0; i < 8; ++i){
        acc.x = fmaf(ww[i], hh[i].x, acc.x);
        acc.y = fmaf(ww[i], hh[i].y, acc.y);
      }
    }
    for (; k < rem; ++k){
      int s = __shfl(s_j, k); float w = __shfl(w_j, k);
      float2 hh = h2[(size_t)s * 64 + lane];
      acc.x = fmaf(w, hh.x, acc.x);
      acc.y = fmaf(w, hh.y, acc.y);
    }
  }
  float inv = 1.f / den;
  float2 bv = ((const float2*)bias)[lane];
  float2 o2;
  o2.x = fmaxf(acc.x * inv + bv.x, 0.f);
  o2.y = fmaxf(acc.y * inv + bv.y, 0.f);
  ((float2*)out)[(size_t)n * 64 + lane] = o2;
}

// ---------------- fused pairwise max-pool + BN stats ----------------
__global__ void pool_bn(const float* __restrict__ in, float* __restrict__ out,
                        float* __restrict__ sums, int Mout){
  __shared__ float s1[256], s2[256];
  int c = threadIdx.x & 127, half = threadIdx.x >> 7;
  float a = 0.f, b = 0.f;
  for (int r = blockIdx.x * 2 + half; r < Mout; r += 512){
    float v0 = in[(size_t)(2 * r) * 128 + c];
    float v1 = in[(size_t)(2 * r + 1) * 128 + c];
    float v = fmaxf(v0, v1);
    out[(size_t)r * 128 + c] = v;
    a += v; b += v * v;
  }
  s1[threadIdx.x] = a; s2[threadIdx.x] = b;
  __syncthreads();
  if (threadIdx.x < 128){
    atomicAdd(&sums[c],       s1[threadIdx.x] + s1[threadIdx.x + 128]);
    atomicAdd(&sums[128 + c], s2[threadIdx.x] + s2[threadIdx.x + 128]);
  }
}

// ---------------- dedupe after pooling ----------------
// useMaskIn=0: base activity = (src0!=dst0) (layer-1 mask computed inline).
// Always writes mask[e] for the next layer.
__global__ void dedupe_kernel(const int* __restrict__ src0, const int* __restrict__ dst0,
                              unsigned char* __restrict__ mask, unsigned int* __restrict__ bitmap,
                              int shift, int log2Npg, int useMaskIn){
  int e = blockIdx.x * blockDim.x + threadIdx.x;
  if (e >= E_TOTAL) return;
  bool act = useMaskIn ? (mask[e] != 0) : (src0[e] != dst0[e]);
  if (!act){ mask[e] = 0; return; }
  int s = src0[e] >> shift, d = dst0[e] >> shift;
  if (s == d){ mask[e] = 0; return; }
  int Npg = 1 << log2Npg;
  unsigned int g = (unsigned int)(s >> log2Npg);
  unsigned int key = (g << (2 * log2Npg)) | ((unsigned int)(s & (Npg - 1)) << log2Npg)
                   | (unsigned int)(d & (Npg - 1));
  unsigned int bit = 1u << (key & 31u);
  unsigned int old = atomicOr(&bitmap[key >> 5], bit);
  mask[e] = (old & bit) ? 0 : 1;
}

// ---------------- final BatchNorm apply ----------------
__global__ void bn_norm(const float* __restrict__ in, const float* __restrict__ sums,
                        float* __restrict__ out, int M){
  int idx = blockIdx.x * blockDim.x + threadIdx.x;
  if (idx >= M * 128) return;
  int c = idx & 127;
  float mu  = sums[c] / (float)M;
  float var = sums[128 + c] / (float)M - mu * mu;
  out[idx] = (in[idx] - mu) * rsqrtf(var + EPS_BN);
}

extern "C" void kernel_launch(void* const* d_in, const int* in_sizes, int n_in,
                              void* d_out, int out_size, void* d_ws, size_t ws_size,
                              hipStream_t stream){
  const float* x0   = (const float*)d_in[0];   // (32768, 64)
  const float* W0   = (const float*)d_in[1];   // (64, 128)
  const float* W1   = (const float*)d_in[2];   // (128, 128)
  const float* W2   = (const float*)d_in[3];   // (128, 128)
  const float* attS = (const float*)d_in[4];   // (3, 128)
  const float* attD = (const float*)d_in[5];   // (3, 128)
  const float* bias = (const float*)d_in[6];   // (3, 128)
  const int*   src0 = (const int*)d_in[7];     // edge_index row 0
  const int*   dst0 = src0 + E_TOTAL;          // edge_index row 1
  float* out = (float*)d_out;                  // (32, 16384) f32

  char* ws = (char*)d_ws;
  float*         Hbuf      = (float*)(ws);                               // 16 MB
  float*         Gbuf      = (float*)(ws + (16u << 20));                 // 16 MB
  float*         Xbuf      = (float*)(ws + (32u << 20));                 //  8 MB
  float*         es        = (float*)(ws + (40u << 20));                 // 128 KB
  float*         ed        = (float*)(ws + (40u << 20) + 131072);        // 128 KB
  int*           csr_src   = (int*)  (ws + (41u << 20));                 //  1 MB
  int*           row_start = (int*)  (ws + (42u << 20));                 // 128 KB
  int*           row_cnt   = (int*)  (ws + (42u << 20) + 131072);        // 128 KB
  unsigned char* mask      = (unsigned char*)(ws + (43u << 20));         // 256 KB
  unsigned int*  bitmap0   = (unsigned int*)(ws + (44u << 20));          //  1 MB
  unsigned int*  bitmap1   = (unsigned int*)(ws + (45u << 20));          // 256 KB
  float*         bnsum0    = (float*)(ws + (45u << 20) + 262144);
  float*         bnsum1    = bnsum0 + 256;
  float*         bnsum2    = bnsum1 + 256;

  // zero bitmaps + bn sums (contiguous)
  hipMemsetAsync(ws + (44u << 20), 0, (1u << 20) + 262144 + 3 * 256 * sizeof(float), stream);

  // ---------------- layer 1: M=32768, K=64, ids at shift 0 ----------------
  int M = 32768;
  gemm_xw<64><<<M / 32, 256, 0, stream>>>(x0, W0, nullptr, 0.f, Hbuf, M);
  attn_terms<<<M / 4, 256, 0, stream>>>(Hbuf, attS, attD, es, ed, M);
  build_csr<<<NGRAPH, 1024, 0, stream>>>(src0, dst0, nullptr, csr_src, row_start, row_cnt,
                                         0, 1024, 0);
  gat_agg<<<M / 4, 256, 0, stream>>>(Hbuf, es, ed, csr_src, row_start, row_cnt, bias, Gbuf, M);
  int Mo = 16384;
  pool_bn<<<256, 256, 0, stream>>>(Gbuf, Xbuf, bnsum0, Mo);
  dedupe_kernel<<<E_TOTAL / 256, 256, 0, stream>>>(src0, dst0, mask, bitmap0, 1, 9, 0);

  // ---------------- layer 2: M=16384, K=128, ids at shift 1 ----------------
  M = 16384;
  gemm_xw<128><<<M / 32, 256, 0, stream>>>(Xbuf, W1, bnsum0, 1.f / (float)M, Hbuf, M);
  attn_terms<<<M / 4, 256, 0, stream>>>(Hbuf, attS + 128, attD + 128, es, ed, M);
  build_csr<<<NGRAPH, 1024, 0, stream>>>(src0, dst0, mask, csr_src, row_start, row_cnt,
                                         1, 512, 1);
  gat_agg<<<M / 4, 256, 0, stream>>>(Hbuf, es, ed, csr_src, row_start, row_cnt,
                                     bias + 128, Gbuf, M);
  Mo = 8192;
  pool_bn<<<256, 256, 0, stream>>>(Gbuf, Xbuf, bnsum1, Mo);
  dedupe_kernel<<<E_TOTAL / 256, 256, 0, stream>>>(src0, dst0, mask, bitmap1, 2, 8, 1);

  // ---------------- layer 3: M=8192, K=128, ids at shift 2 ----------------
  M = 8192;
  gemm_xw<128><<<M / 32, 256, 0, stream>>>(Xbuf, W2, bnsum1, 1.f / (float)M, Hbuf, M);
  attn_terms<<<M / 4, 256, 0, stream>>>(Hbuf, attS + 256, attD + 256, es, ed, M);
  build_csr<<<NGRAPH, 1024, 0, stream>>>(src0, dst0, mask, csr_src, row_start, row_cnt,
                                         2, 256, 1);
  gat_agg<<<M / 4, 256, 0, stream>>>(Hbuf, es, ed, csr_src, row_start, row_cnt,
                                     bias + 256, Gbuf, M);
  Mo = 4096;
  pool_bn<<<256, 256, 0, stream>>>(Gbuf, Xbuf, bnsum2, Mo);
  bn_norm<<<(Mo * 128) / 256, 256, 0, stream>>>(Xbuf, bnsum2, out, Mo);
}

// Round 3
// 273.707 us; speedup vs baseline: 1.7114x; 1.0609x over previous
//
#include <hip/hip_runtime.h>

// Problem constants: B=32 graphs, N=1024 nodes/graph, F=64, D=128, DEG=8
#define E_TOTAL 262144     // B*N*DEG
#define NGRAPH  32
#define EPG     8192       // edges per graph
#define EPS_BN  1e-5f

__device__ __forceinline__ float lrelu(float x){ return x > 0.f ? x : 0.2f * x; }

// ---------------- GEMM + attention terms: C = bn(A) @ W, es = C.a_s, ed = C.a_d ----------
// block 256 = 64 channel-pairs x 4 row-groups (one wave per row-group); 32 rows/block.
// A tile staged TRANSPOSED in LDS (stride 36 => aligned float4 broadcast reads).
// bnsums != nullptr: normalize A columns with batch stats (sums[c], sums[K+c]).
// Epilogue: row r's 128 channels live in wave rg's 64 lanes -> shuffle-reduce es/ed.
template<int K>
__global__ __launch_bounds__(256)
void gemm_attn(const float* __restrict__ A, const float* __restrict__ W,
               const float* __restrict__ bnsums, float invM,
               const float* __restrict__ a_s, const float* __restrict__ a_d,
               float* __restrict__ C, float* __restrict__ es, float* __restrict__ ed){
  __shared__ float Ws[64 * 128];    // 32 KB
  __shared__ float As_t[64 * 36];   // 9 KB, [kk][row] padded
  __shared__ float bnmu[K], bnrs[K];
  int tid = threadIdx.x;
  if (tid < K){
    float mu = 0.f, rs = 1.f;
    if (bnsums){
      mu = bnsums[tid] * invM;
      float var = bnsums[K + tid] * invM - mu * mu;
      rs = rsqrtf(var + EPS_BN);
    }
    bnmu[tid] = mu; bnrs[tid] = rs;
  }
  int row0 = blockIdx.x * 32;
  int c2 = tid & 63, rg = tid >> 6;
  float2 acc[8];
  #pragma unroll
  for (int i = 0; i < 8; ++i){ acc[i].x = 0.f; acc[i].y = 0.f; }

  for (int k0 = 0; k0 < K; k0 += 64){
    __syncthreads();
    for (int i = tid; i < 64 * 128; i += 256)
      Ws[i] = W[(size_t)(k0 + (i >> 7)) * 128 + (i & 127)];
    #pragma unroll
    for (int it = 0; it < 8; ++it){
      int i = it * 256 + tid;
      int r = i >> 6, kk = i & 63;
      float v = A[(size_t)(row0 + r) * K + k0 + kk];
      v = (v - bnmu[k0 + kk]) * bnrs[k0 + kk];
      As_t[kk * 36 + r] = v;
    }
    __syncthreads();
    #pragma unroll 8
    for (int kk = 0; kk < 64; ++kk){
      float2 w = *(float2*)&Ws[kk * 128 + c2 * 2];
      float4 a0 = *(float4*)&As_t[kk * 36 + rg * 8];
      float4 a1 = *(float4*)&As_t[kk * 36 + rg * 8 + 4];
      acc[0].x = fmaf(a0.x, w.x, acc[0].x); acc[0].y = fmaf(a0.x, w.y, acc[0].y);
      acc[1].x = fmaf(a0.y, w.x, acc[1].x); acc[1].y = fmaf(a0.y, w.y, acc[1].y);
      acc[2].x = fmaf(a0.z, w.x, acc[2].x); acc[2].y = fmaf(a0.z, w.y, acc[2].y);
      acc[3].x = fmaf(a0.w, w.x, acc[3].x); acc[3].y = fmaf(a0.w, w.y, acc[3].y);
      acc[4].x = fmaf(a1.x, w.x, acc[4].x); acc[4].y = fmaf(a1.x, w.y, acc[4].y);
      acc[5].x = fmaf(a1.y, w.x, acc[5].x); acc[5].y = fmaf(a1.y, w.y, acc[5].y);
      acc[6].x = fmaf(a1.z, w.x, acc[6].x); acc[6].y = fmaf(a1.z, w.y, acc[6].y);
      acc[7].x = fmaf(a1.w, w.x, acc[7].x); acc[7].y = fmaf(a1.w, w.y, acc[7].y);
    }
  }
  float2 as2 = ((const float2*)a_s)[c2];
  float2 ad2 = ((const float2*)a_d)[c2];
  float2* C2 = (float2*)C;
  #pragma unroll
  for (int i = 0; i < 8; ++i){
    int r = row0 + rg * 8 + i;
    C2[(size_t)r * 64 + c2] = acc[i];
    float e1 = acc[i].x * as2.x + acc[i].y * as2.y;
    float e2 = acc[i].x * ad2.x + acc[i].y * ad2.y;
    #pragma unroll
    for (int o = 32; o; o >>= 1){ e1 += __shfl_xor(e1, o); e2 += __shfl_xor(e2, o); }
    if (c2 == 0){ es[r] = e1; ed[r] = e2; }
  }
}

// ---------------- per-graph counting sort by dst (+ inline dedupe for next layer) --------
// one block (1024 thr) per graph. act_i from maskIn (or src!=dst if maskIn==null).
// If maskOut != null: maskOut[e] = act_i && s2!=d2 && first-claim of (s2,d2) bit.
__global__ __launch_bounds__(1024)
void build_csr(const int* __restrict__ src0, const int* __restrict__ dst0,
               const unsigned char* __restrict__ maskIn,
               int* __restrict__ csr_src, int* __restrict__ row_start,
               int* __restrict__ row_cnt, int shift, int Npg,
               unsigned char* __restrict__ maskOut, unsigned int* __restrict__ bitmap,
               int shiftN, int log2NpgN){
  __shared__ int cnt[1024];
  __shared__ int pos[1024];
  __shared__ int wsum[16];
  int g = blockIdx.x, t = threadIdx.x;
  int ebase = g * EPG;
  if (t < Npg) cnt[t] = 0;
  __syncthreads();
  unsigned keep = 0;
  #pragma unroll
  for (int k = 0; k < 8; ++k){
    int e = ebase + t + k * 1024;
    int sv = src0[e], dv = dst0[e];
    bool act = maskIn ? (maskIn[e] != 0) : (sv != dv);
    if (act){
      keep |= (1u << k);
      atomicAdd(&cnt[(dv >> shift) & (Npg - 1)], 1);
    }
    if (maskOut){
      unsigned char m2 = 0;
      if (act){
        int s2 = sv >> shiftN, d2 = dv >> shiftN;
        if (s2 != d2){
          int NpgN = 1 << log2NpgN;
          unsigned int gg = (unsigned int)(s2 >> log2NpgN);
          unsigned int key = (gg << (2 * log2NpgN)) |
                             ((unsigned int)(s2 & (NpgN - 1)) << log2NpgN) |
                             (unsigned int)(d2 & (NpgN - 1));
          unsigned int bit = 1u << (key & 31u);
          unsigned int old = atomicOr(&bitmap[key >> 5], bit);
          m2 = (old & bit) ? 0 : 1;
        }
      }
      maskOut[e] = m2;
    }
  }
  __syncthreads();
  int c = (t < Npg) ? cnt[t] : 0;
  int lane = t & 63, w = t >> 6;
  int v = c;
  #pragma unroll
  for (int o = 1; o < 64; o <<= 1){
    int u = __shfl_up(v, o);
    if (lane >= o) v += u;
  }
  if (lane == 63) wsum[w] = v;
  __syncthreads();
  if (t == 0){
    int run = 0;
    #pragma unroll
    for (int i = 0; i < 16; ++i){ int x = wsum[i]; wsum[i] = run; run += x; }
  }
  __syncthreads();
  int excl = v - c + wsum[w];
  if (t < Npg){
    pos[t] = excl;
    row_start[g * Npg + t] = ebase + excl;
    row_cnt[g * Npg + t]   = c;
  }
  __syncthreads();
  #pragma unroll
  for (int k = 0; k < 8; ++k){
    if (keep & (1u << k)){
      int e = ebase + t + k * 1024;
      int d = (dst0[e] >> shift) & (Npg - 1);
      int p = atomicAdd(&pos[d], 1);
      csr_src[ebase + p] = src0[e] >> shift;
    }
  }
}

// ---------------- GAT softmax-aggregate + bias + ReLU + pairwise max-pool ----------------
// one wave per dst node; block 256 -> nodes 4b..4b+3 = pool pairs; writes M/2 pooled rows.
__global__ void gat_pool(const float* __restrict__ h, const float* __restrict__ es,
                         const float* __restrict__ ed, const int* __restrict__ csr_src,
                         const int* __restrict__ row_start, const int* __restrict__ row_cnt,
                         const float* __restrict__ bias, float* __restrict__ xout, int M){
  __shared__ float2 osh[4][64];
  int lane = threadIdx.x & 63;
  int wave = threadIdx.x >> 6;
  int n = blockIdx.x * 4 + wave;
  int start = row_start[n];
  int cnt   = row_cnt[n];
  float edn = ed[n];
  float selfl = lrelu(es[n] + edn);

  // phase A: online softmax stats, lane-parallel
  float m_l = -1e30f, d_l = 0.f;
  for (int c0 = 0; c0 < cnt; c0 += 64){
    int j = c0 + lane;
    if (j < cnt){
      int s = csr_src[start + j];
      float l = lrelu(es[s] + edn);
      float mn = fmaxf(m_l, l);
      d_l = d_l * __expf(m_l - mn) + __expf(l - mn);
      m_l = mn;
    }
  }
  #pragma unroll
  for (int o = 32; o; o >>= 1){
    float m2 = __shfl_xor(m_l, o), d2 = __shfl_xor(d_l, o);
    float mn = fmaxf(m_l, m2);
    d_l = d_l * __expf(m_l - mn) + d2 * __expf(m2 - mn);
    m_l = mn;
  }
  float mf  = fmaxf(m_l, selfl);
  float den = d_l * __expf(m_l - mf) + __expf(selfl - mf);

  // phase B: weighted accumulation, 8 gathers in flight via shfl-broadcast indices
  const float2* h2 = (const float2*)h;
  float sw = __expf(selfl - mf);
  float2 hv = h2[(size_t)n * 64 + lane];
  float2 acc; acc.x = sw * hv.x; acc.y = sw * hv.y;
  for (int c0 = 0; c0 < cnt; c0 += 64){
    int j = c0 + lane;
    int s_j = 0; float w_j = 0.f;
    if (j < cnt){
      s_j = csr_src[start + j];
      w_j = __expf(lrelu(es[s_j] + edn) - mf);
    }
    int rem = min(64, cnt - c0);
    int k = 0;
    for (; k + 8 <= rem; k += 8){
      int ss[8]; float ww[8]; float2 hh[8];
      #pragma unroll
      for (int i = 0; i < 8; ++i){ ss[i] = __shfl(s_j, k + i); ww[i] = __shfl(w_j, k + i); }
      #pragma unroll
      for (int i = 0; i < 8; ++i){ hh[i] = h2[(size_t)ss[i] * 64 + lane]; }
      #pragma unroll
      for (int i = 0; i < 8; ++i){
        acc.x = fmaf(ww[i], hh[i].x, acc.x);
        acc.y = fmaf(ww[i], hh[i].y, acc.y);
      }
    }
    for (; k < rem; ++k){
      int s = __shfl(s_j, k); float w = __shfl(w_j, k);
      float2 hh = h2[(size_t)s * 64 + lane];
      acc.x = fmaf(w, hh.x, acc.x);
      acc.y = fmaf(w, hh.y, acc.y);
    }
  }
  float inv = 1.f / den;
  float2 bv = ((const float2*)bias)[lane];
  float2 o2;
  o2.x = fmaxf(acc.x * inv + bv.x, 0.f);
  o2.y = fmaxf(acc.y * inv + bv.y, 0.f);
  osh[wave][lane] = o2;
  __syncthreads();
  if (wave < 2){
    float2 a = osh[2 * wave][lane], b = osh[2 * wave + 1][lane];
    float2 p; p.x = fmaxf(a.x, b.x); p.y = fmaxf(a.y, b.y);
    ((float2*)xout)[(size_t)(blockIdx.x * 2 + wave) * 64 + lane] = p;
  }
}

// ---------------- BN stats over pooled X ----------------
__global__ void bn_stats(const float* __restrict__ x, float* __restrict__ sums, int M){
  __shared__ float s1[256], s2[256];
  int c = threadIdx.x & 127, half = threadIdx.x >> 7;
  float a = 0.f, b = 0.f;
  for (int r = blockIdx.x * 2 + half; r < M; r += 256){
    float v = x[(size_t)r * 128 + c];
    a += v; b += v * v;
  }
  s1[threadIdx.x] = a; s2[threadIdx.x] = b;
  __syncthreads();
  if (threadIdx.x < 128){
    atomicAdd(&sums[c],       s1[threadIdx.x] + s1[threadIdx.x + 128]);
    atomicAdd(&sums[128 + c], s2[threadIdx.x] + s2[threadIdx.x + 128]);
  }
}

// ---------------- final BatchNorm apply ----------------
__global__ void bn_norm(const float* __restrict__ in, const float* __restrict__ sums,
                        float* __restrict__ out, int M){
  int idx = blockIdx.x * blockDim.x + threadIdx.x;
  if (idx >= M * 128) return;
  int c = idx & 127;
  float mu  = sums[c] / (float)M;
  float var = sums[128 + c] / (float)M - mu * mu;
  out[idx] = (in[idx] - mu) * rsqrtf(var + EPS_BN);
}

extern "C" void kernel_launch(void* const* d_in, const int* in_sizes, int n_in,
                              void* d_out, int out_size, void* d_ws, size_t ws_size,
                              hipStream_t stream){
  const float* x0   = (const float*)d_in[0];
  const float* W0   = (const float*)d_in[1];
  const float* W1   = (const float*)d_in[2];
  const float* W2   = (const float*)d_in[3];
  const float* attS = (const float*)d_in[4];
  const float* attD = (const float*)d_in[5];
  const float* bias = (const float*)d_in[6];
  const int*   src0 = (const int*)d_in[7];
  const int*   dst0 = src0 + E_TOTAL;
  float* out = (float*)d_out;                  // (32, 16384) f32

  char* ws = (char*)d_ws;
  float*         Hbuf      = (float*)(ws);                               // 16 MB
  float*         Xbuf      = (float*)(ws + (16u << 20));                 //  8 MB (pooled)
  float*         es        = (float*)(ws + (24u << 20));                 // 128 KB
  float*         ed        = (float*)(ws + (24u << 20) + 131072);        // 128 KB
  int*           csr_src   = (int*)  (ws + (25u << 20));                 //  1 MB
  int*           row_start = (int*)  (ws + (26u << 20));                 // 128 KB
  int*           row_cnt   = (int*)  (ws + (26u << 20) + 131072);        // 128 KB
  unsigned char* mask2     = (unsigned char*)(ws + (27u << 20));         // 256 KB
  unsigned char* mask3     = (unsigned char*)(ws + (27u << 20) + 262144);// 256 KB
  unsigned int*  bitmap0   = (unsigned int*)(ws + (28u << 20));          //  1 MB
  unsigned int*  bitmap1   = (unsigned int*)(ws + (29u << 20));          // 256 KB
  float*         bnsum0    = (float*)(ws + (29u << 20) + 262144);
  float*         bnsum1    = bnsum0 + 256;
  float*         bnsum2    = bnsum1 + 256;

  // zero bitmaps + bn sums (contiguous region starting at bitmap0)
  hipMemsetAsync(ws + (28u << 20), 0, (1u << 20) + 262144 + 3 * 256 * sizeof(float), stream);

  // ---------------- layer 1: M=32768, K=64, ids at shift 0 ----------------
  int M = 32768;
  gemm_attn<64><<<M / 32, 256, 0, stream>>>(x0, W0, nullptr, 0.f, attS, attD, Hbuf, es, ed);
  build_csr<<<NGRAPH, 1024, 0, stream>>>(src0, dst0, nullptr, csr_src, row_start, row_cnt,
                                         0, 1024, mask2, bitmap0, 1, 9);
  gat_pool<<<M / 4, 256, 0, stream>>>(Hbuf, es, ed, csr_src, row_start, row_cnt, bias, Xbuf, M);
  bn_stats<<<128, 256, 0, stream>>>(Xbuf, bnsum0, M / 2);

  // ---------------- layer 2: M=16384, K=128, ids at shift 1 ----------------
  M = 16384;
  gemm_attn<128><<<M / 32, 256, 0, stream>>>(Xbuf, W1, bnsum0, 1.f / (float)M,
                                             attS + 128, attD + 128, Hbuf, es, ed);
  build_csr<<<NGRAPH, 1024, 0, stream>>>(src0, dst0, mask2, csr_src, row_start, row_cnt,
                                         1, 512, mask3, bitmap1, 2, 8);
  gat_pool<<<M / 4, 256, 0, stream>>>(Hbuf, es, ed, csr_src, row_start, row_cnt,
                                      bias + 128, Xbuf, M);
  bn_stats<<<128, 256, 0, stream>>>(Xbuf, bnsum1, M / 2);

  // ---------------- layer 3: M=8192, K=128, ids at shift 2 ----------------
  M = 8192;
  gemm_attn<128><<<M / 32, 256, 0, stream>>>(Xbuf, W2, bnsum1, 1.f / (float)M,
                                             attS + 256, attD + 256, Hbuf, es, ed);
  build_csr<<<NGRAPH, 1024, 0, stream>>>(src0, dst0, mask3, csr_src, row_start, row_cnt,
                                         2, 256, nullptr, nullptr, 0, 0);
  gat_pool<<<M / 4, 256, 0, stream>>>(Hbuf, es, ed, csr_src, row_start, row_cnt,
                                      bias + 256, Xbuf, M);
  bn_stats<<<128, 256, 0, stream>>>(Xbuf, bnsum2, M / 2);
  bn_norm<<<(M / 2 * 128) / 256, 256, 0, stream>>>(Xbuf, bnsum2, out, M / 2);
}